// Round 12
// baseline (606.625 us; speedup 1.0000x reference)
//
#include <hip/hip_runtime.h>
#include <hip/hip_fp16.h>

#define NN 100000
#define NE 1600000
#define DIM 64
#define NL 3
#define SLOPE 0.2f

#define BSH 9                      // 512 nodes per bucket
#define NBUCK ((NN + 511) >> BSH)  // 196
#define EPT 16
#define TILE (256 * EPT)  // 4096 edges per partition tile
#define MT 128            // transform M-tile

static __device__ __forceinline__ float lrelu(float x) { return x > 0.f ? x : SLOPE * x; }

// ---------------- CSR build: LDS-binned two-level counting sort ----------------

// per-block LDS histogram over dst buckets (int4 loads), one global atomic per block x bucket
__global__ __launch_bounds__(256) void k_bucket_hist(const int* __restrict__ ei, int* __restrict__ bcnt) {
    __shared__ int h[256];
    int t = threadIdx.x;
    h[t] = 0;
    __syncthreads();
    const int4* d4 = (const int4*)(ei + NE);
    int idx = blockIdx.x * 256 + t;
    if (idx < NE / 4) {
        int4 v = d4[idx];
        atomicAdd(&h[v.x >> BSH], 1);
        atomicAdd(&h[v.y >> BSH], 1);
        atomicAdd(&h[v.z >> BSH], 1);
        atomicAdd(&h[v.w >> BSH], 1);
    }
    __syncthreads();
    if (t < NBUCK && h[t]) atomicAdd(&bcnt[t], h[t]);
}

__global__ void k_bucket_scan(const int* __restrict__ bcnt, int* __restrict__ bbase, int* __restrict__ bcur,
                              int* __restrict__ offs) {
    __shared__ int sm[256];
    int t = threadIdx.x;
    sm[t] = (t < NBUCK) ? bcnt[t] : 0;
    __syncthreads();
    for (int off = 1; off < 256; off <<= 1) {
        int x = (t >= off) ? sm[t - off] : 0;
        __syncthreads();
        sm[t] += x;
        __syncthreads();
    }
    if (t < NBUCK) {
        int ex = (t == 0) ? 0 : sm[t - 1];
        bbase[t] = ex;
        bcur[t] = ex;
    }
    if (t == 0) {
        bbase[NBUCK] = NE;
        offs[NN] = NE;
    }
}

// rank tile edges per bucket in LDS, reorder tile so same-bucket edges are contiguous,
// claim global space (1 atomic per bucket per tile), copy out coalesced.
__global__ __launch_bounds__(256) void k_partition(const int* __restrict__ ei, int* __restrict__ bcur,
                                                   int2* __restrict__ pairs) {
    __shared__ int2 tile[TILE];
    __shared__ int cnt[256], ofsx[256], gdel[256], sm[256];
    int t = threadIdx.x;
    int ts = blockIdx.x * TILE;
    int tilecnt = NE - ts;
    if (tilecnt > TILE) tilecnt = TILE;
    cnt[t] = 0;
    __syncthreads();
    int srcv[EPT], dstv[EPT], rk[EPT];
    int ebase = ts + t * EPT;
    if (ts + TILE <= NE) {  // full tile: vectorized
#pragma unroll
        for (int j = 0; j < EPT / 4; j++) {
            int4 sv = *(const int4*)(ei + ebase + j * 4);
            int4 dv = *(const int4*)(ei + NE + ebase + j * 4);
            srcv[j * 4 + 0] = sv.x;
            srcv[j * 4 + 1] = sv.y;
            srcv[j * 4 + 2] = sv.z;
            srcv[j * 4 + 3] = sv.w;
            dstv[j * 4 + 0] = dv.x;
            dstv[j * 4 + 1] = dv.y;
            dstv[j * 4 + 2] = dv.z;
            dstv[j * 4 + 3] = dv.w;
        }
#pragma unroll
        for (int k = 0; k < EPT; k++) rk[k] = atomicAdd(&cnt[dstv[k] >> BSH], 1);
    } else {  // tail tile: scalar guarded
#pragma unroll
        for (int k = 0; k < EPT; k++) {
            int e = ebase + k;
            if (e < NE) {
                srcv[k] = ei[e];
                dstv[k] = ei[NE + e];
                rk[k] = atomicAdd(&cnt[dstv[k] >> BSH], 1);
            } else {
                rk[k] = -1;
            }
        }
    }
    __syncthreads();
    sm[t] = cnt[t];
    __syncthreads();
    for (int off = 1; off < 256; off <<= 1) {
        int x = (t >= off) ? sm[t - off] : 0;
        __syncthreads();
        sm[t] += x;
        __syncthreads();
    }
    ofsx[t] = (t == 0) ? 0 : sm[t - 1];
    __syncthreads();
    if (ts + TILE <= NE) {
#pragma unroll
        for (int k = 0; k < EPT; k++) tile[ofsx[dstv[k] >> BSH] + rk[k]] = make_int2(srcv[k], dstv[k]);
    } else {
#pragma unroll
        for (int k = 0; k < EPT; k++)
            if (rk[k] >= 0) tile[ofsx[dstv[k] >> BSH] + rk[k]] = make_int2(srcv[k], dstv[k]);
    }
    if (t < NBUCK && cnt[t]) gdel[t] = atomicAdd(&bcur[t], cnt[t]) - ofsx[t];
    __syncthreads();
    for (int i = t; i < tilecnt; i += 256) {
        int2 p = tile[i];
        pairs[gdel[p.y >> BSH] + i] = p;
    }
}

// one block per bucket: per-node counts + scan in LDS, then scatter src into the
// bucket's contiguous csr segment (L2-resident). Emits global offs coalesced.
// Also feeds the 64-bin degree histogram for the degree-sorted node permutation.
__global__ __launch_bounds__(256) void k_node_csr(const int2* __restrict__ pairs, const int* __restrict__ bbase,
                                                  int* __restrict__ offs, int* __restrict__ csr,
                                                  int* __restrict__ dcnt) {
    __shared__ int deg[512], sofs[512], scur[512], sm[256], dh[64];
    int t = threadIdx.x;
    int b = blockIdx.x;
    int nodeBase = b << BSH;
    int nNodes = NN - nodeBase;
    if (nNodes > 512) nNodes = 512;
    deg[t] = 0;
    deg[t + 256] = 0;
    if (t < 64) dh[t] = 0;
    __syncthreads();
    int ebeg = bbase[b], eend = bbase[b + 1];
    for (int i = ebeg + t; i < eend; i += 256) atomicAdd(&deg[pairs[i].y - nodeBase], 1);
    __syncthreads();
    int a0 = deg[2 * t], a1 = deg[2 * t + 1];
    sm[t] = a0 + a1;
    __syncthreads();
    for (int off = 1; off < 256; off <<= 1) {
        int x = (t >= off) ? sm[t - off] : 0;
        __syncthreads();
        sm[t] += x;
        __syncthreads();
    }
    int base = (t == 0) ? 0 : sm[t - 1];
    sofs[2 * t] = base;
    sofs[2 * t + 1] = base + a0;
    scur[2 * t] = 0;
    scur[2 * t + 1] = 0;
    __syncthreads();
    for (int n = t; n < nNodes; n += 256) {
        offs[nodeBase + n] = ebeg + sofs[n];
        int d = deg[n];
        atomicAdd(&dh[d > 63 ? 63 : d], 1);
    }
    for (int i = ebeg + t; i < eend; i += 256) {
        int2 p = pairs[i];
        int ln = p.y - nodeBase;
        int r = atomicAdd(&scur[ln], 1);
        csr[ebeg + sofs[ln] + r] = p.x;
    }
    __syncthreads();
    if (t < 64 && dh[t]) atomicAdd(&dcnt[t], dh[t]);
}

// exclusive scan of the 64 degree bins
__global__ void k_degscan(const int* __restrict__ dcnt, int* __restrict__ dcur) {
    __shared__ int sm[64];
    int t = threadIdx.x;
    sm[t] = dcnt[t];
    __syncthreads();
    for (int off = 1; off < 64; off <<= 1) {
        int x = (t >= off) ? sm[t - off] : 0;
        __syncthreads();
        sm[t] += x;
        __syncthreads();
    }
    dcur[t] = (t == 0) ? 0 : sm[t - 1];
}

// scatter node ids into degree-sorted order (affects wave grouping only, not math)
__global__ __launch_bounds__(256) void k_degscatter(const int* __restrict__ offs, int* __restrict__ dcur,
                                                    int* __restrict__ nodeperm) {
    int i = blockIdx.x * 256 + threadIdx.x;
    if (i < NN) {
        int d = offs[i + 1] - offs[i];
        if (d > 63) d = 63;
        int pos = atomicAdd(&dcur[d], 1);
        nodeperm[pos] = i;
    }
}

// ---------------- per-layer passes ----------------

// LDS-tiled register-blocked GEMM: 128-node M-tile, thread tile 8 rows x 4 cols.
// Writes hw in fp16 (aggregation input); attention logits from fp32 acc (exact).
__global__ __launch_bounds__(256) void k_transform(const float* __restrict__ h, const float* __restrict__ W,
                                                   const float* __restrict__ avs, const float* __restrict__ avd,
                                                   ushort* __restrict__ hw, float* __restrict__ als,
                                                   float* __restrict__ ald) {
    __shared__ float sh[MT][65];
    __shared__ float sw[64][64];
    int t = threadIdx.x;
    int tx = t & 15, ty = t >> 4;
    int base = blockIdx.x * MT;
    int rows = NN - base;
    if (rows > MT) rows = MT;
    {
        const float4* Wv = (const float4*)W;
        float4* swv = (float4*)sw;
        for (int i = t; i < 1024; i += 256) swv[i] = Wv[i];
    }
    for (int i = t; i < MT * 16; i += 256) {
        int r = i >> 4, cs = i & 15;
        float4 v = (r < rows) ? *(const float4*)(h + (size_t)(base + r) * 64 + cs * 4)
                              : make_float4(0.f, 0.f, 0.f, 0.f);
        sh[r][cs * 4 + 0] = v.x;
        sh[r][cs * 4 + 1] = v.y;
        sh[r][cs * 4 + 2] = v.z;
        sh[r][cs * 4 + 3] = v.w;
    }
    __syncthreads();
    float acc[8][4] = {};
    int r0 = ty * 8;
#pragma unroll 4
    for (int k = 0; k < 64; k++) {
        float4 b = *(const float4*)(&sw[k][tx * 4]);
#pragma unroll
        for (int r = 0; r < 8; r++) {
            float a = sh[r0 + r][k];
            acc[r][0] = fmaf(a, b.x, acc[r][0]);
            acc[r][1] = fmaf(a, b.y, acc[r][1]);
            acc[r][2] = fmaf(a, b.z, acc[r][2]);
            acc[r][3] = fmaf(a, b.w, acc[r][3]);
        }
    }
    float4 as4 = *(const float4*)(avs + tx * 4);
    float4 ad4 = *(const float4*)(avd + tx * 4);
#pragma unroll
    for (int r = 0; r < 8; r++) {
        int row = r0 + r;
        bool ok = row < rows;
        if (ok) {
            __half2 h0 = __floats2half2_rn(acc[r][0], acc[r][1]);
            __half2 h1 = __floats2half2_rn(acc[r][2], acc[r][3]);
            uint2 u;
            u.x = __builtin_bit_cast(unsigned int, h0);
            u.y = __builtin_bit_cast(unsigned int, h1);
            *(uint2*)(hw + (size_t)(base + row) * 64 + tx * 4) = u;
        }
        float ps = acc[r][0] * as4.x + acc[r][1] * as4.y + acc[r][2] * as4.z + acc[r][3] * as4.w;
        float pd = acc[r][0] * ad4.x + acc[r][1] * ad4.y + acc[r][2] * ad4.z + acc[r][3] * ad4.w;
#pragma unroll
        for (int off = 1; off <= 8; off <<= 1) {
            ps += __shfl_xor(ps, off);
            pd += __shfl_xor(pd, off);
        }
        if (tx == 0 && ok) {
            als[base + row] = ps;
            ald[base + row] = pd;
        }
    }
}

// 16-lane group per dst node, nodes taken in degree-sorted order (nodeperm) so the
// 4 groups of a wave run equal chunk counts (no divergence). No-max softmax (logits
// O(10), fp32 exp safe). Phase 2: 16B fp16 loads — lanes 0-7 cover edge A's row,
// lanes 8-15 edge B's (2 rows per load instr); acc[8] per lane, xor-8 reduce at end.
__global__ __launch_bounds__(256) void k_aggregate(const ushort* __restrict__ hw, const float* __restrict__ als,
                                                   const float* __restrict__ ald, const int* __restrict__ offs,
                                                   const int* __restrict__ csr, const int* __restrict__ nodeperm,
                                                   const float* __restrict__ bv, float* __restrict__ out) {
    int t = threadIdx.x, wave = t >> 6, lane = t & 63;
    int grp = lane >> 4, l = lane & 15;
    int grpbase = grp << 4;
    int gid = blockIdx.x * 16 + wave * 4 + grp;
    if (gid >= NN) return;
    int i = nodeperm[gid];
    int halfsel = l >> 3;       // 0: edge A, 1: edge B
    int dimoff = (l & 7) * 8;   // this lane's 8 dims
    float ad = ald[i];
    float spart = 0.f;
    float acc[8] = {};
    int beg = offs[i], end = offs[i + 1];
    for (int cb = beg; cb < end; cb += 16) {
        int cnt = end - cb;
        if (cnt > 16) cnt = 16;
        // phase 1: per-edge weight, lane = edge; padding lanes p=0
        int src = 0;
        float p = 0.f;
        if (l < cnt) {
            src = csr[cb + l];
            p = __expf(lrelu(als[src] + ad));
        }
        spart += p;
        // phase 2: 4 edges per step via 2x 16B loads (2 rows per load across halves)
        int pairs2 = (cnt + 1) >> 1;
        for (int j = 0; j < pairs2; j += 2) {
            int ea = grpbase + j * 2 + halfsel;
            int eb = ea + 2;
            int sa = __shfl(src, ea);
            float pa = __shfl(p, ea);
            int sb = __shfl(src, eb);
            float pb = __shfl(p, eb);
            uint4 ua = *(const uint4*)(hw + (size_t)sa * 64 + dimoff);
            uint4 ub = *(const uint4*)(hw + (size_t)sb * 64 + dimoff);
            float2 f0 = __half22float2(__builtin_bit_cast(__half2, ua.x));
            float2 f1 = __half22float2(__builtin_bit_cast(__half2, ua.y));
            float2 f2 = __half22float2(__builtin_bit_cast(__half2, ua.z));
            float2 f3 = __half22float2(__builtin_bit_cast(__half2, ua.w));
            acc[0] = fmaf(pa, f0.x, acc[0]);
            acc[1] = fmaf(pa, f0.y, acc[1]);
            acc[2] = fmaf(pa, f1.x, acc[2]);
            acc[3] = fmaf(pa, f1.y, acc[3]);
            acc[4] = fmaf(pa, f2.x, acc[4]);
            acc[5] = fmaf(pa, f2.y, acc[5]);
            acc[6] = fmaf(pa, f3.x, acc[6]);
            acc[7] = fmaf(pa, f3.y, acc[7]);
            float2 g0 = __half22float2(__builtin_bit_cast(__half2, ub.x));
            float2 g1 = __half22float2(__builtin_bit_cast(__half2, ub.y));
            float2 g2 = __half22float2(__builtin_bit_cast(__half2, ub.z));
            float2 g3 = __half22float2(__builtin_bit_cast(__half2, ub.w));
            acc[0] = fmaf(pb, g0.x, acc[0]);
            acc[1] = fmaf(pb, g0.y, acc[1]);
            acc[2] = fmaf(pb, g1.x, acc[2]);
            acc[3] = fmaf(pb, g1.y, acc[3]);
            acc[4] = fmaf(pb, g2.x, acc[4]);
            acc[5] = fmaf(pb, g2.y, acc[5]);
            acc[6] = fmaf(pb, g3.x, acc[6]);
            acc[7] = fmaf(pb, g3.y, acc[7]);
        }
    }
    // combine the two half-group accumulators (lanes l and l^8 hold same dims)
#pragma unroll
    for (int k = 0; k < 8; k++) acc[k] += __shfl_xor(acc[k], 8);
    // reduce s over the 16-lane group
    float s = spart;
#pragma unroll
    for (int off = 1; off <= 8; off <<= 1) s += __shfl_xor(s, off);
    // self loop (both halves compute identically; harmless duplicate)
    float ps = __expf(lrelu(als[i] + ad));
    s += ps;
    uint4 uh = *(const uint4*)(hw + (size_t)i * 64 + dimoff);
    float2 h0 = __half22float2(__builtin_bit_cast(__half2, uh.x));
    float2 h1 = __half22float2(__builtin_bit_cast(__half2, uh.y));
    float2 h2 = __half22float2(__builtin_bit_cast(__half2, uh.z));
    float2 h3 = __half22float2(__builtin_bit_cast(__half2, uh.w));
    acc[0] = fmaf(ps, h0.x, acc[0]);
    acc[1] = fmaf(ps, h0.y, acc[1]);
    acc[2] = fmaf(ps, h1.x, acc[2]);
    acc[3] = fmaf(ps, h1.y, acc[3]);
    acc[4] = fmaf(ps, h2.x, acc[4]);
    acc[5] = fmaf(ps, h2.y, acc[5]);
    acc[6] = fmaf(ps, h3.x, acc[6]);
    acc[7] = fmaf(ps, h3.y, acc[7]);
    if (halfsel == 0) {  // lanes 0-7 write the full row (8 dims each)
        float inv = 1.f / s;
        const float4 b0 = *(const float4*)(bv + dimoff);
        const float4 b1 = *(const float4*)(bv + dimoff + 4);
        float4 o0, o1;
        o0.x = fminf(fmaxf(fmaf(acc[0], inv, b0.x), -1.f), 1.f);
        o0.y = fminf(fmaxf(fmaf(acc[1], inv, b0.y), -1.f), 1.f);
        o0.z = fminf(fmaxf(fmaf(acc[2], inv, b0.z), -1.f), 1.f);
        o0.w = fminf(fmaxf(fmaf(acc[3], inv, b0.w), -1.f), 1.f);
        o1.x = fminf(fmaxf(fmaf(acc[4], inv, b1.x), -1.f), 1.f);
        o1.y = fminf(fmaxf(fmaf(acc[5], inv, b1.y), -1.f), 1.f);
        o1.z = fminf(fmaxf(fmaf(acc[6], inv, b1.z), -1.f), 1.f);
        o1.w = fminf(fmaxf(fmaf(acc[7], inv, b1.w), -1.f), 1.f);
        *(float4*)(out + (size_t)i * 64 + dimoff) = o0;
        *(float4*)(out + (size_t)i * 64 + dimoff + 4) = o1;
    }
}

// ---------------- launch ----------------

extern "C" void kernel_launch(void* const* d_in, const int* in_sizes, int n_in, void* d_out, int out_size,
                              void* d_ws, size_t ws_size, hipStream_t stream) {
    const float* x = (const float*)d_in[0];
    const int* ei = (const int*)d_in[1];  // [2, NE] int32
    const float* W = (const float*)d_in[2];
    const float* a_s = (const float*)d_in[3];
    const float* a_d = (const float*)d_in[4];
    const float* b = (const float*)d_in[5];
    float* out = (float*)d_out;

    char* w = (char*)d_ws;
    auto alloc = [&](size_t bytes) -> char* {
        char* p = w;
        w += (bytes + 255) & ~(size_t)255;
        return p;
    };
    int* bcnt = (int*)alloc((256 + 64) * 4);  // bcnt[256] + dcnt[64], one memset
    int* dcnt = bcnt + 256;
    int* bbase = (int*)alloc(257 * 4);
    int* bcur = (int*)alloc(256 * 4);
    int* dcur = (int*)alloc(64 * 4);
    int* offs = (int*)alloc((NN + 1) * 4);
    int* nodeperm = (int*)alloc(NN * 4);
    int* csr = (int*)alloc((size_t)NE * 4);
    // pairs (12.8 MB, CSR-build phase) aliases the als/ald/hw(fp16) region (layer phase)
    size_t layer_bytes = (size_t)(2 * NN) * 4 + (size_t)NN * DIM * 2;
    size_t build_bytes = (size_t)NE * 8;
    char* region = alloc(layer_bytes > build_bytes ? layer_bytes : build_bytes);
    int2* pairs = (int2*)region;
    float* als = (float*)region;
    float* ald = als + NN;
    ushort* hwb = (ushort*)(ald + NN);

    // CSR by dst + degree-sorted node permutation (same inputs every call)
    hipMemsetAsync(bcnt, 0, (256 + 64) * 4, stream);
    k_bucket_hist<<<(NE / 4 + 255) / 256, 256, 0, stream>>>(ei, bcnt);
    k_bucket_scan<<<1, 256, 0, stream>>>(bcnt, bbase, bcur, offs);
    k_partition<<<(NE + TILE - 1) / TILE, 256, 0, stream>>>(ei, bcur, pairs);
    k_node_csr<<<NBUCK, 256, 0, stream>>>(pairs, bbase, offs, csr, dcnt);
    k_degscan<<<1, 64, 0, stream>>>(dcnt, dcur);
    k_degscatter<<<(NN + 255) / 256, 256, 0, stream>>>(offs, dcur, nodeperm);

    // 3 GAT layers; d_out doubles as the h ping buffer (h dead once hw computed)
    const float* hin = x;
    for (int l = 0; l < NL; l++) {
        k_transform<<<(NN + MT - 1) / MT, 256, 0, stream>>>(hin, W + l * DIM * DIM, a_s + l * DIM, a_d + l * DIM,
                                                            hwb, als, ald);
        k_aggregate<<<(NN + 15) / 16, 256, 0, stream>>>(hwb, als, ald, offs, csr, nodeperm, b + l * DIM, out);
        hin = out;
    }
}

// Round 13
// 362.971 us; speedup vs baseline: 1.6713x; 1.6713x over previous
//
#include <hip/hip_runtime.h>
#include <hip/hip_fp16.h>

#define NN 100000
#define NE 1600000
#define DIM 64
#define NL 3
#define SLOPE 0.2f

#define BSH 9                      // 512 nodes per bucket
#define NBUCK ((NN + 511) >> BSH)  // 196
#define EPT 16
#define TILE (256 * EPT)  // 4096 edges per partition tile
#define MT 128            // transform M-tile

static __device__ __forceinline__ float lrelu(float x) { return x > 0.f ? x : SLOPE * x; }

// ---------------- CSR build: LDS-binned two-level counting sort ----------------

// per-block LDS histogram over dst buckets (int4 loads), one global atomic per block x bucket
__global__ __launch_bounds__(256) void k_bucket_hist(const int* __restrict__ ei, int* __restrict__ bcnt) {
    __shared__ int h[256];
    int t = threadIdx.x;
    h[t] = 0;
    __syncthreads();
    const int4* d4 = (const int4*)(ei + NE);
    int idx = blockIdx.x * 256 + t;
    if (idx < NE / 4) {
        int4 v = d4[idx];
        atomicAdd(&h[v.x >> BSH], 1);
        atomicAdd(&h[v.y >> BSH], 1);
        atomicAdd(&h[v.z >> BSH], 1);
        atomicAdd(&h[v.w >> BSH], 1);
    }
    __syncthreads();
    if (t < NBUCK && h[t]) atomicAdd(&bcnt[t], h[t]);
}

__global__ void k_bucket_scan(const int* __restrict__ bcnt, int* __restrict__ bbase, int* __restrict__ bcur,
                              int* __restrict__ offs) {
    __shared__ int sm[256];
    int t = threadIdx.x;
    sm[t] = (t < NBUCK) ? bcnt[t] : 0;
    __syncthreads();
    for (int off = 1; off < 256; off <<= 1) {
        int x = (t >= off) ? sm[t - off] : 0;
        __syncthreads();
        sm[t] += x;
        __syncthreads();
    }
    if (t < NBUCK) {
        int ex = (t == 0) ? 0 : sm[t - 1];
        bbase[t] = ex;
        bcur[t] = ex;
    }
    if (t == 0) {
        bbase[NBUCK] = NE;
        offs[NN] = NE;
    }
}

// rank tile edges per bucket in LDS, reorder tile so same-bucket edges are contiguous,
// claim global space (1 atomic per bucket per tile), copy out coalesced.
__global__ __launch_bounds__(256) void k_partition(const int* __restrict__ ei, int* __restrict__ bcur,
                                                   int2* __restrict__ pairs) {
    __shared__ int2 tile[TILE];
    __shared__ int cnt[256], ofsx[256], gdel[256], sm[256];
    int t = threadIdx.x;
    int ts = blockIdx.x * TILE;
    int tilecnt = NE - ts;
    if (tilecnt > TILE) tilecnt = TILE;
    cnt[t] = 0;
    __syncthreads();
    int srcv[EPT], dstv[EPT], rk[EPT];
    int ebase = ts + t * EPT;
    if (ts + TILE <= NE) {  // full tile: vectorized
#pragma unroll
        for (int j = 0; j < EPT / 4; j++) {
            int4 sv = *(const int4*)(ei + ebase + j * 4);
            int4 dv = *(const int4*)(ei + NE + ebase + j * 4);
            srcv[j * 4 + 0] = sv.x;
            srcv[j * 4 + 1] = sv.y;
            srcv[j * 4 + 2] = sv.z;
            srcv[j * 4 + 3] = sv.w;
            dstv[j * 4 + 0] = dv.x;
            dstv[j * 4 + 1] = dv.y;
            dstv[j * 4 + 2] = dv.z;
            dstv[j * 4 + 3] = dv.w;
        }
#pragma unroll
        for (int k = 0; k < EPT; k++) rk[k] = atomicAdd(&cnt[dstv[k] >> BSH], 1);
    } else {  // tail tile: scalar guarded
#pragma unroll
        for (int k = 0; k < EPT; k++) {
            int e = ebase + k;
            if (e < NE) {
                srcv[k] = ei[e];
                dstv[k] = ei[NE + e];
                rk[k] = atomicAdd(&cnt[dstv[k] >> BSH], 1);
            } else {
                rk[k] = -1;
            }
        }
    }
    __syncthreads();
    sm[t] = cnt[t];
    __syncthreads();
    for (int off = 1; off < 256; off <<= 1) {
        int x = (t >= off) ? sm[t - off] : 0;
        __syncthreads();
        sm[t] += x;
        __syncthreads();
    }
    ofsx[t] = (t == 0) ? 0 : sm[t - 1];
    __syncthreads();
    if (ts + TILE <= NE) {
#pragma unroll
        for (int k = 0; k < EPT; k++) tile[ofsx[dstv[k] >> BSH] + rk[k]] = make_int2(srcv[k], dstv[k]);
    } else {
#pragma unroll
        for (int k = 0; k < EPT; k++)
            if (rk[k] >= 0) tile[ofsx[dstv[k] >> BSH] + rk[k]] = make_int2(srcv[k], dstv[k]);
    }
    if (t < NBUCK && cnt[t]) gdel[t] = atomicAdd(&bcur[t], cnt[t]) - ofsx[t];
    __syncthreads();
    for (int i = t; i < tilecnt; i += 256) {
        int2 p = tile[i];
        pairs[gdel[p.y >> BSH] + i] = p;
    }
}

// one block per bucket: per-node counts + scan in LDS, scatter src into the bucket's
// contiguous csr segment (L2-resident), emit offs coalesced, AND degree-sort the
// bucket's nodes into nodeperm via a 64-bin LDS counting sort (wave-0 shfl scan) —
// equal-degree wave quads for k_aggregate with zero global atomic contention.
__global__ __launch_bounds__(256) void k_node_csr(const int2* __restrict__ pairs, const int* __restrict__ bbase,
                                                  int* __restrict__ offs, int* __restrict__ csr,
                                                  int* __restrict__ nodeperm) {
    __shared__ int deg[512], sofs[512], scur[512], sm[256], dh[64], dbase[64];
    int t = threadIdx.x;
    int b = blockIdx.x;
    int nodeBase = b << BSH;
    int nNodes = NN - nodeBase;
    if (nNodes > 512) nNodes = 512;
    deg[t] = 0;
    deg[t + 256] = 0;
    if (t < 64) dh[t] = 0;
    __syncthreads();
    int ebeg = bbase[b], eend = bbase[b + 1];
    for (int i = ebeg + t; i < eend; i += 256) atomicAdd(&deg[pairs[i].y - nodeBase], 1);
    __syncthreads();
    int a0 = deg[2 * t], a1 = deg[2 * t + 1];
    sm[t] = a0 + a1;
    __syncthreads();
    for (int off = 1; off < 256; off <<= 1) {
        int x = (t >= off) ? sm[t - off] : 0;
        __syncthreads();
        sm[t] += x;
        __syncthreads();
    }
    int base = (t == 0) ? 0 : sm[t - 1];
    sofs[2 * t] = base;
    sofs[2 * t + 1] = base + a0;
    scur[2 * t] = 0;
    scur[2 * t + 1] = 0;
    __syncthreads();
    for (int n = t; n < nNodes; n += 256) {
        offs[nodeBase + n] = ebeg + sofs[n];
        int d = deg[n];
        atomicAdd(&dh[d > 63 ? 63 : d], 1);
    }
    for (int i = ebeg + t; i < eend; i += 256) {
        int2 p = pairs[i];
        int ln = p.y - nodeBase;
        int r = atomicAdd(&scur[ln], 1);
        csr[ebeg + sofs[ln] + r] = p.x;
    }
    __syncthreads();
    // 64-bin exclusive scan of degree histogram (wave 0), then rank-scatter nodes
    if (t < 64) {
        int v = dh[t];
        int inc = v;
#pragma unroll
        for (int off = 1; off < 64; off <<= 1) {
            int x = __shfl_up(inc, off);
            if (t >= off) inc += x;
        }
        dbase[t] = inc - v;
        dh[t] = 0;  // reuse as rank counters
    }
    __syncthreads();
    for (int n = t; n < nNodes; n += 256) {
        int d = deg[n];
        if (d > 63) d = 63;
        int r = atomicAdd(&dh[d], 1);
        nodeperm[nodeBase + dbase[d] + r] = nodeBase + n;
    }
}

// ---------------- per-layer passes ----------------

// LDS-tiled register-blocked GEMM: 128-node M-tile, thread tile 8 rows x 4 cols.
// Writes hw in fp16 (aggregation input); attention logits from fp32 acc (exact).
__global__ __launch_bounds__(256) void k_transform(const float* __restrict__ h, const float* __restrict__ W,
                                                   const float* __restrict__ avs, const float* __restrict__ avd,
                                                   ushort* __restrict__ hw, float* __restrict__ als,
                                                   float* __restrict__ ald) {
    __shared__ float sh[MT][65];
    __shared__ float sw[64][64];
    int t = threadIdx.x;
    int tx = t & 15, ty = t >> 4;
    int base = blockIdx.x * MT;
    int rows = NN - base;
    if (rows > MT) rows = MT;
    {
        const float4* Wv = (const float4*)W;
        float4* swv = (float4*)sw;
        for (int i = t; i < 1024; i += 256) swv[i] = Wv[i];
    }
    for (int i = t; i < MT * 16; i += 256) {
        int r = i >> 4, cs = i & 15;
        float4 v = (r < rows) ? *(const float4*)(h + (size_t)(base + r) * 64 + cs * 4)
                              : make_float4(0.f, 0.f, 0.f, 0.f);
        sh[r][cs * 4 + 0] = v.x;
        sh[r][cs * 4 + 1] = v.y;
        sh[r][cs * 4 + 2] = v.z;
        sh[r][cs * 4 + 3] = v.w;
    }
    __syncthreads();
    float acc[8][4] = {};
    int r0 = ty * 8;
#pragma unroll 4
    for (int k = 0; k < 64; k++) {
        float4 b = *(const float4*)(&sw[k][tx * 4]);
#pragma unroll
        for (int r = 0; r < 8; r++) {
            float a = sh[r0 + r][k];
            acc[r][0] = fmaf(a, b.x, acc[r][0]);
            acc[r][1] = fmaf(a, b.y, acc[r][1]);
            acc[r][2] = fmaf(a, b.z, acc[r][2]);
            acc[r][3] = fmaf(a, b.w, acc[r][3]);
        }
    }
    float4 as4 = *(const float4*)(avs + tx * 4);
    float4 ad4 = *(const float4*)(avd + tx * 4);
#pragma unroll
    for (int r = 0; r < 8; r++) {
        int row = r0 + r;
        bool ok = row < rows;
        if (ok) {
            __half2 h0 = __floats2half2_rn(acc[r][0], acc[r][1]);
            __half2 h1 = __floats2half2_rn(acc[r][2], acc[r][3]);
            uint2 u;
            u.x = __builtin_bit_cast(unsigned int, h0);
            u.y = __builtin_bit_cast(unsigned int, h1);
            *(uint2*)(hw + (size_t)(base + row) * 64 + tx * 4) = u;
        }
        float ps = acc[r][0] * as4.x + acc[r][1] * as4.y + acc[r][2] * as4.z + acc[r][3] * as4.w;
        float pd = acc[r][0] * ad4.x + acc[r][1] * ad4.y + acc[r][2] * ad4.z + acc[r][3] * ad4.w;
#pragma unroll
        for (int off = 1; off <= 8; off <<= 1) {
            ps += __shfl_xor(ps, off);
            pd += __shfl_xor(pd, off);
        }
        if (tx == 0 && ok) {
            als[base + row] = ps;
            ald[base + row] = pd;
        }
    }
}

// 16-lane group per dst node, nodes taken in per-bucket degree-sorted order (nodeperm)
// so the 4 groups of a wave run equal chunk counts. No-max softmax (logits O(10), fp32
// exp safe). Phase 2: 16B fp16 loads — lanes 0-7 cover edge A's row, lanes 8-15 edge
// B's (2 rows per load instr); acc[8] per lane, xor-8 reduce at end.
__global__ __launch_bounds__(256) void k_aggregate(const ushort* __restrict__ hw, const float* __restrict__ als,
                                                   const float* __restrict__ ald, const int* __restrict__ offs,
                                                   const int* __restrict__ csr, const int* __restrict__ nodeperm,
                                                   const float* __restrict__ bv, float* __restrict__ out) {
    int t = threadIdx.x, wave = t >> 6, lane = t & 63;
    int grp = lane >> 4, l = lane & 15;
    int grpbase = grp << 4;
    int gid = blockIdx.x * 16 + wave * 4 + grp;
    if (gid >= NN) return;
    int i = nodeperm[gid];
    int halfsel = l >> 3;       // 0: edge A, 1: edge B
    int dimoff = (l & 7) * 8;   // this lane's 8 dims
    float ad = ald[i];
    float spart = 0.f;
    float acc[8] = {};
    int beg = offs[i], end = offs[i + 1];
    for (int cb = beg; cb < end; cb += 16) {
        int cnt = end - cb;
        if (cnt > 16) cnt = 16;
        // phase 1: per-edge weight, lane = edge; padding lanes p=0
        int src = 0;
        float p = 0.f;
        if (l < cnt) {
            src = csr[cb + l];
            p = __expf(lrelu(als[src] + ad));
        }
        spart += p;
        // phase 2: 4 edges per step via 2x 16B loads (2 rows per load across halves)
        int pairs2 = (cnt + 1) >> 1;
        for (int j = 0; j < pairs2; j += 2) {
            int ea = grpbase + j * 2 + halfsel;
            int eb = ea + 2;
            int sa = __shfl(src, ea);
            float pa = __shfl(p, ea);
            int sb = __shfl(src, eb);
            float pb = __shfl(p, eb);
            uint4 ua = *(const uint4*)(hw + (size_t)sa * 64 + dimoff);
            uint4 ub = *(const uint4*)(hw + (size_t)sb * 64 + dimoff);
            float2 f0 = __half22float2(__builtin_bit_cast(__half2, ua.x));
            float2 f1 = __half22float2(__builtin_bit_cast(__half2, ua.y));
            float2 f2 = __half22float2(__builtin_bit_cast(__half2, ua.z));
            float2 f3 = __half22float2(__builtin_bit_cast(__half2, ua.w));
            acc[0] = fmaf(pa, f0.x, acc[0]);
            acc[1] = fmaf(pa, f0.y, acc[1]);
            acc[2] = fmaf(pa, f1.x, acc[2]);
            acc[3] = fmaf(pa, f1.y, acc[3]);
            acc[4] = fmaf(pa, f2.x, acc[4]);
            acc[5] = fmaf(pa, f2.y, acc[5]);
            acc[6] = fmaf(pa, f3.x, acc[6]);
            acc[7] = fmaf(pa, f3.y, acc[7]);
            float2 g0 = __half22float2(__builtin_bit_cast(__half2, ub.x));
            float2 g1 = __half22float2(__builtin_bit_cast(__half2, ub.y));
            float2 g2 = __half22float2(__builtin_bit_cast(__half2, ub.z));
            float2 g3 = __half22float2(__builtin_bit_cast(__half2, ub.w));
            acc[0] = fmaf(pb, g0.x, acc[0]);
            acc[1] = fmaf(pb, g0.y, acc[1]);
            acc[2] = fmaf(pb, g1.x, acc[2]);
            acc[3] = fmaf(pb, g1.y, acc[3]);
            acc[4] = fmaf(pb, g2.x, acc[4]);
            acc[5] = fmaf(pb, g2.y, acc[5]);
            acc[6] = fmaf(pb, g3.x, acc[6]);
            acc[7] = fmaf(pb, g3.y, acc[7]);
        }
    }
    // combine the two half-group accumulators (lanes l and l^8 hold same dims)
#pragma unroll
    for (int k = 0; k < 8; k++) acc[k] += __shfl_xor(acc[k], 8);
    // reduce s over the 16-lane group
    float s = spart;
#pragma unroll
    for (int off = 1; off <= 8; off <<= 1) s += __shfl_xor(s, off);
    // self loop (both halves compute identically; harmless duplicate)
    float ps = __expf(lrelu(als[i] + ad));
    s += ps;
    uint4 uh = *(const uint4*)(hw + (size_t)i * 64 + dimoff);
    float2 h0 = __half22float2(__builtin_bit_cast(__half2, uh.x));
    float2 h1 = __half22float2(__builtin_bit_cast(__half2, uh.y));
    float2 h2 = __half22float2(__builtin_bit_cast(__half2, uh.z));
    float2 h3 = __half22float2(__builtin_bit_cast(__half2, uh.w));
    acc[0] = fmaf(ps, h0.x, acc[0]);
    acc[1] = fmaf(ps, h0.y, acc[1]);
    acc[2] = fmaf(ps, h1.x, acc[2]);
    acc[3] = fmaf(ps, h1.y, acc[3]);
    acc[4] = fmaf(ps, h2.x, acc[4]);
    acc[5] = fmaf(ps, h2.y, acc[5]);
    acc[6] = fmaf(ps, h3.x, acc[6]);
    acc[7] = fmaf(ps, h3.y, acc[7]);
    if (halfsel == 0) {  // lanes 0-7 write the full row (8 dims each)
        float inv = 1.f / s;
        const float4 b0 = *(const float4*)(bv + dimoff);
        const float4 b1 = *(const float4*)(bv + dimoff + 4);
        float4 o0, o1;
        o0.x = fminf(fmaxf(fmaf(acc[0], inv, b0.x), -1.f), 1.f);
        o0.y = fminf(fmaxf(fmaf(acc[1], inv, b0.y), -1.f), 1.f);
        o0.z = fminf(fmaxf(fmaf(acc[2], inv, b0.z), -1.f), 1.f);
        o0.w = fminf(fmaxf(fmaf(acc[3], inv, b0.w), -1.f), 1.f);
        o1.x = fminf(fmaxf(fmaf(acc[4], inv, b1.x), -1.f), 1.f);
        o1.y = fminf(fmaxf(fmaf(acc[5], inv, b1.y), -1.f), 1.f);
        o1.z = fminf(fmaxf(fmaf(acc[6], inv, b1.z), -1.f), 1.f);
        o1.w = fminf(fmaxf(fmaf(acc[7], inv, b1.w), -1.f), 1.f);
        *(float4*)(out + (size_t)i * 64 + dimoff) = o0;
        *(float4*)(out + (size_t)i * 64 + dimoff + 4) = o1;
    }
}

// ---------------- launch ----------------

extern "C" void kernel_launch(void* const* d_in, const int* in_sizes, int n_in, void* d_out, int out_size,
                              void* d_ws, size_t ws_size, hipStream_t stream) {
    const float* x = (const float*)d_in[0];
    const int* ei = (const int*)d_in[1];  // [2, NE] int32
    const float* W = (const float*)d_in[2];
    const float* a_s = (const float*)d_in[3];
    const float* a_d = (const float*)d_in[4];
    const float* b = (const float*)d_in[5];
    float* out = (float*)d_out;

    char* w = (char*)d_ws;
    auto alloc = [&](size_t bytes) -> char* {
        char* p = w;
        w += (bytes + 255) & ~(size_t)255;
        return p;
    };
    int* bcnt = (int*)alloc(256 * 4);
    int* bbase = (int*)alloc(257 * 4);
    int* bcur = (int*)alloc(256 * 4);
    int* offs = (int*)alloc((NN + 1) * 4);
    int* nodeperm = (int*)alloc(NN * 4);
    int* csr = (int*)alloc((size_t)NE * 4);
    // pairs (12.8 MB, CSR-build phase) aliases the als/ald/hw(fp16) region (layer phase)
    size_t layer_bytes = (size_t)(2 * NN) * 4 + (size_t)NN * DIM * 2;
    size_t build_bytes = (size_t)NE * 8;
    char* region = alloc(layer_bytes > build_bytes ? layer_bytes : build_bytes);
    int2* pairs = (int2*)region;
    float* als = (float*)region;
    float* ald = als + NN;
    ushort* hwb = (ushort*)(ald + NN);

    // CSR by dst + per-bucket degree-sorted node permutation (same inputs every call)
    hipMemsetAsync(bcnt, 0, 256 * 4, stream);
    k_bucket_hist<<<(NE / 4 + 255) / 256, 256, 0, stream>>>(ei, bcnt);
    k_bucket_scan<<<1, 256, 0, stream>>>(bcnt, bbase, bcur, offs);
    k_partition<<<(NE + TILE - 1) / TILE, 256, 0, stream>>>(ei, bcur, pairs);
    k_node_csr<<<NBUCK, 256, 0, stream>>>(pairs, bbase, offs, csr, nodeperm);

    // 3 GAT layers; d_out doubles as the h ping buffer (h dead once hw computed)
    const float* hin = x;
    for (int l = 0; l < NL; l++) {
        k_transform<<<(NN + MT - 1) / MT, 256, 0, stream>>>(hin, W + l * DIM * DIM, a_s + l * DIM, a_d + l * DIM,
                                                            hwb, als, ald);
        k_aggregate<<<(NN + 15) / 16, 256, 0, stream>>>(hwb, als, ald, offs, csr, nodeperm, b + l * DIM, out);
        hin = out;
    }
}